// Round 10
// baseline (201.827 us; speedup 1.0000x reference)
//
#include <hip/hip_runtime.h>
#include <hip/hip_bf16.h>
#include <stdint.h>

#define BROWS 16384
#define DIM   256
#define BM    128
#define BN    128
#define NBM   (BROWS / BM)      // 128 row blocks
#define NBN   (BROWS / BN)      // 128 col blocks
#define NCHUNK 256              // 64-wide column chunks per row

#define LOG2E 1.44269504088896340736f

typedef __attribute__((ext_vector_type(8))) int  i32x8;
typedef __attribute__((ext_vector_type(4))) float f32x4;
typedef unsigned char uchar;

#if __has_builtin(__builtin_amdgcn_exp2f)
#define EXP2(x) __builtin_amdgcn_exp2f(x)   // bare v_exp_f32; |arg|<=1.45 -> exact
#else
#define EXP2(x) exp2f(x)
#endif

// Tiled fp8 layout ("frag-major"): row r, byte-in-row (c*32+b), c in 0..7:
//   addr = (r>>4)*4096 + c*512 + (r&15)*32 + b
// A wave's MFMA fragment load (lane l: row g*16+(l&15), K-chunk c) is then
// base + l*32 -> 2KB contiguous per (frag, K-half) = perfectly coalesced.

// ---------------- Kernel A: normalize BOTH matrices -> tiled fp8 + diag -----
__global__ void normalize_both(const float* __restrict__ o,
                               const float* __restrict__ t,
                               uchar* __restrict__ o8,
                               uchar* __restrict__ t8,
                               float* __restrict__ dlog) {
  int row  = blockIdx.x * 4 + (threadIdx.x >> 6);
  int lane = threadIdx.x & 63;
  float4 a = *(reinterpret_cast<const float4*>(o + (size_t)row * DIM) + lane);
  float4 b = *(reinterpret_cast<const float4*>(t + (size_t)row * DIM) + lane);
  float sso = a.x * a.x + a.y * a.y + a.z * a.z + a.w * a.w;
  float sst = b.x * b.x + b.y * b.y + b.z * b.z + b.w * b.w;
  float d   = a.x * b.x + a.y * b.y + a.z * b.z + a.w * b.w;
#pragma unroll
  for (int m = 1; m < 64; m <<= 1) {
    sso += __shfl_xor(sso, m);
    sst += __shfl_xor(sst, m);
    d   += __shfl_xor(d, m);
  }
  float ro = rsqrtf(sso);
  float rt = rsqrtf(sst);
  if (lane == 0) dlog[row] = d * ro * rt;
  float qo = ro * LOG2E;
  int wo = 0, wt = 0;
  wo = __builtin_amdgcn_cvt_pk_fp8_f32(a.x * qo, a.y * qo, wo, false);
  wo = __builtin_amdgcn_cvt_pk_fp8_f32(a.z * qo, a.w * qo, wo, true);
  wt = __builtin_amdgcn_cvt_pk_fp8_f32(b.x * rt, b.y * rt, wt, false);
  wt = __builtin_amdgcn_cvt_pk_fp8_f32(b.z * rt, b.w * rt, wt, true);
  // lane's 4B word sits at row-byte lane*4 -> c = lane>>3, b = (lane&7)*4
  size_t taddr = (size_t)(row >> 4) * 4096 + (size_t)((lane >> 3) * 512) +
                 (size_t)((row & 15) * 32) + (size_t)((lane & 7) * 4);
  *reinterpret_cast<int*>(o8 + taddr) = wo;
  *reinterpret_cast<int*>(t8 + taddr) = wt;
}

// ---------------- Kernel B: fp8 GEMM (MX scale=1) + exp2 + partial sums -----
// 128x128 C-tile, 4 waves 2x2 (wave tile 64x64), mfma_scale 16x16x128 fp8,
// identity E8M0 scales. NO LDS, NO barriers, NO staging: fragments load
// straight from the frag-major tiled global layout (L2/L3-resident, 4 MB per
// matrix) as one i32x8 each = 2x coalesced global_load_dwordx4 (2KB/wave).
// Frag (HW-verified r5/r6): lane l holds row (l&15), K-bytes [(l>>4)*32,+32).
// C/D: col = lane&15, row = (lane>>4)*4 + reg.
__global__ __launch_bounds__(256, 4) void gemm_expsum(
    const uchar* __restrict__ A8,   // ohat fp8 tiled, pre-scaled by log2e
    const uchar* __restrict__ B8,   // that fp8 tiled (rows = logits cols)
    float* __restrict__ partial) {
  // XCD-chunked bijective swizzle (16384 % 8 == 0): each XCD gets a
  // contiguous 2048-block range -> 16 bn panels + A fully L2-resident.
  int b   = blockIdx.x;
  int swz = (b & 7) * (NBM * NBN / 8) + (b >> 3);
  int bm  = swz & (NBM - 1);
  int bn  = swz >> 7;

  int tid  = threadIdx.x;
  int lane = tid & 63;
  int wid  = tid >> 6;
  int wr   = wid >> 1;      // wave row 0..1
  int wc   = wid & 1;       // wave col 0..1

  // per-lane fragment base: group g = bm*8 + wr*4 + m  (A), bn*8 + wc*4 + n (B)
  const uchar* At = A8 + (size_t)(bm * 8 + wr * 4) * 4096 + (size_t)lane * 32;
  const uchar* Bt = B8 + (size_t)(bn * 8 + wc * 4) * 4096 + (size_t)lane * 32;

  f32x4 acc[4][4];
#pragma unroll
  for (int m = 0; m < 4; ++m)
#pragma unroll
    for (int n = 0; n < 4; ++n) acc[m][n] = (f32x4){0.f, 0.f, 0.f, 0.f};

#pragma unroll
  for (int kt = 0; kt < 2; ++kt) {   // K = 256 fp8 = 2 x 128
    i32x8 bf[4];
#pragma unroll
    for (int n = 0; n < 4; ++n)
      bf[n] = *reinterpret_cast<const i32x8*>(Bt + n * 4096 + kt * 2048);
#pragma unroll
    for (int m = 0; m < 4; ++m) {
      i32x8 af = *reinterpret_cast<const i32x8*>(At + m * 4096 + kt * 2048);
#pragma unroll
      for (int n = 0; n < 4; ++n)
        acc[m][n] = __builtin_amdgcn_mfma_scale_f32_16x16x128_f8f6f4(
            af, bf[n], acc[m][n], 0, 0,               // cbsz=fp8, blgp=fp8
            0, 0x7F7F7F7F, 0, 0x7F7F7F7F);            // identity E8M0 scales
    }
  }

  // ---- epilogue: S = log2e * logit (bounded) -> v[j] = sum_n 2^S ----
  float v[16];
#pragma unroll
  for (int j = 0; j < 16; ++j) {
    int m = j >> 2, r = j & 3;
    v[j] = EXP2(acc[m][0][r]) + EXP2(acc[m][1][r]) +
           EXP2(acc[m][2][r]) + EXP2(acc[m][3][r]);
  }
  // butterfly-bisect over the 16 fragment columns: 15 shfl; lane ends with the
  // full column-sum for output row-index j = lane&15. (HW-verified r5/r6.)
#pragma unroll
  for (int s = 0; s < 4; ++s) {
    const int len = 16 >> s;
    const int bit = (lane >> s) & 1;
#pragma unroll
    for (int t = 0; t < 8; ++t) {
      if (t < (len >> 1)) {
        float a = v[2 * t], b2 = v[2 * t + 1];
        float recv = __shfl_xor(bit ? a : b2, 1 << s);
        v[t] = (bit ? b2 : a) + recv;
      }
    }
  }
  {
    int j     = lane & 15;
    int sub   = lane >> 4;
    int row   = bm * BM + wr * 64 + (j >> 2) * 16 + sub * 4 + (j & 3);
    int chunk = (bn << 1) | wc;
    partial[(size_t)row * NCHUNK + chunk] = v[0];
  }
}

// ---------------- Kernel C: per-row finish: log(sum) - exact diag ----------
__global__ void row_finish(const float* __restrict__ partial,
                           const float* __restrict__ dlog,
                           float* __restrict__ rowloss) {
  int row  = blockIdx.x * 4 + (threadIdx.x >> 6);
  int lane = threadIdx.x & 63;
  float4 p = *(reinterpret_cast<const float4*>(partial + (size_t)row * NCHUNK) + lane);
  float s  = p.x + p.y + p.z + p.w;
#pragma unroll
  for (int m = 1; m < 64; m <<= 1) s += __shfl_xor(s, m);
  if (lane == 0) rowloss[row] = logf(s) - dlog[row];
}

// ---------------- Kernel D: mean over rows -> d_out[0] ----------------
__global__ void final_reduce(const float* __restrict__ rl, float* __restrict__ out) {
  __shared__ float sm[16];
  float s = 0.f;
  for (int i = threadIdx.x; i < BROWS; i += 1024) s += rl[i];
#pragma unroll
  for (int m = 1; m < 64; m <<= 1) s += __shfl_xor(s, m);
  int wid = threadIdx.x >> 6, lane = threadIdx.x & 63;
  if (lane == 0) sm[wid] = s;
  __syncthreads();
  if (wid == 0) {
    float v = (lane < 16) ? sm[lane] : 0.f;
#pragma unroll
    for (int m = 1; m < 16; m <<= 1) v += __shfl_xor(v, m);
    if (lane == 0) out[0] = v / (float)BROWS;
  }
}

extern "C" void kernel_launch(void* const* d_in, const int* in_sizes, int n_in,
                              void* d_out, int out_size, void* d_ws, size_t ws_size,
                              hipStream_t stream) {
  const float* outputs = (const float*)d_in[0];
  const float* targets = (const float*)d_in[1];
  float* out = (float*)d_out;
  char* ws = (char*)d_ws;

  uchar* o8      = (uchar*)ws;                                      // 4 MB (tiled)
  uchar* t8      = (uchar*)(ws + (size_t)4 * 1024 * 1024);          // 4 MB (tiled)
  float* partial = (float*)(ws + (size_t)8 * 1024 * 1024);          // 16 MB
  float* dlog    = (float*)(ws + (size_t)24 * 1024 * 1024);         // 64 KB
  float* rowloss = (float*)(ws + (size_t)24 * 1024 * 1024 + 65536); // 64 KB

  normalize_both<<<BROWS / 4, 256, 0, stream>>>(outputs, targets, o8, t8, dlog);
  gemm_expsum<<<NBM * NBN, 256, 0, stream>>>(o8, t8, partial);
  row_finish<<<BROWS / 4, 256, 0, stream>>>(partial, dlog, rowloss);
  final_reduce<<<1, 1024, 0, stream>>>(rowloss, out);
}

// Round 11
// 85.033 us; speedup vs baseline: 2.3735x; 2.3735x over previous
//
#include <hip/hip_runtime.h>
#include <hip/hip_bf16.h>
#include <stdint.h>

#define BROWS 16384
#define DIM   256
#define BM    128               // A rows per block (persistent in registers)
#define NBM   (BROWS / BM)      // 128 row blocks
#define NBNR  8                 // col-range blocks; each covers 16 tiles x 128
#define NTILE 16                // B tiles per block
#define NCHUNK 16               // per-row partial chunks (8 bnr x 2 wc)

#define LOG2E 1.44269504088896340736f

typedef __attribute__((ext_vector_type(8))) int  i32x8;
typedef __attribute__((ext_vector_type(4))) float f32x4;
typedef unsigned char uchar;

#if __has_builtin(__builtin_amdgcn_exp2f)
#define EXP2(x) __builtin_amdgcn_exp2f(x)   // bare v_exp_f32; |arg|<=1.45 -> exact
#else
#define EXP2(x) exp2f(x)
#endif

// Tiled fp8 layout ("frag-major", HW-verified r10): row r, byte (c*32+b):
//   addr = (r>>4)*4096 + c*512 + (r&15)*32 + b
// Wave frag load (lane l: row 16g+(l&15), K-chunk kt*4+(l>>4)) =
//   g*4096 + kt*2048 + l*32  -> 2KB contiguous, perfectly coalesced.

// ---------------- Kernel A: normalize BOTH matrices -> tiled fp8 + diag -----
__global__ void normalize_both(const float* __restrict__ o,
                               const float* __restrict__ t,
                               uchar* __restrict__ o8,
                               uchar* __restrict__ t8,
                               float* __restrict__ dlog) {
  int row  = blockIdx.x * 4 + (threadIdx.x >> 6);
  int lane = threadIdx.x & 63;
  float4 a = *(reinterpret_cast<const float4*>(o + (size_t)row * DIM) + lane);
  float4 b = *(reinterpret_cast<const float4*>(t + (size_t)row * DIM) + lane);
  float sso = a.x * a.x + a.y * a.y + a.z * a.z + a.w * a.w;
  float sst = b.x * b.x + b.y * b.y + b.z * b.z + b.w * b.w;
  float d   = a.x * b.x + a.y * b.y + a.z * b.z + a.w * b.w;
#pragma unroll
  for (int m = 1; m < 64; m <<= 1) {
    sso += __shfl_xor(sso, m);
    sst += __shfl_xor(sst, m);
    d   += __shfl_xor(d, m);
  }
  float ro = rsqrtf(sso);
  float rt = rsqrtf(sst);
  if (lane == 0) dlog[row] = d * ro * rt;
  float qo = ro * LOG2E;
  int wo = 0, wt = 0;
  wo = __builtin_amdgcn_cvt_pk_fp8_f32(a.x * qo, a.y * qo, wo, false);
  wo = __builtin_amdgcn_cvt_pk_fp8_f32(a.z * qo, a.w * qo, wo, true);
  wt = __builtin_amdgcn_cvt_pk_fp8_f32(b.x * rt, b.y * rt, wt, false);
  wt = __builtin_amdgcn_cvt_pk_fp8_f32(b.z * rt, b.w * rt, wt, true);
  size_t taddr = (size_t)(row >> 4) * 4096 + (size_t)((lane >> 3) * 512) +
                 (size_t)((row & 15) * 32) + (size_t)((lane & 7) * 4);
  *reinterpret_cast<int*>(o8 + taddr) = wo;
  *reinterpret_cast<int*>(t8 + taddr) = wt;
}

// ---------------- Kernel B: persistent-A fp8 GEMM + exp2 + fused row sums ---
// Block = 128 A-rows x 2048 cols (16 tiles of 128). 4 waves 2x2 per tile
// (wave tile 64x64). A-frags register-resident (af[4][2], loaded once).
// B streams from tiled global, software ping-pong (bfA/bfB). NO LDS, NO
// barriers, NO acc block: per (m,n), 2 chained MFMAs from a zero C feed exp2
// directly; v[16] accumulates across all 16 tiles; ONE butterfly at the end.
// Frag (HW-verified r5/r6/r10): lane l holds row (l&15), K-bytes [(l>>4)*32).
// C/D: col = lane&15, row = (lane>>4)*4 + reg.
__global__ __launch_bounds__(256, 2) void gemm_expsum(
    const uchar* __restrict__ A8,   // ohat fp8 tiled, pre-scaled by log2e
    const uchar* __restrict__ B8,   // that fp8 tiled (rows = logits cols)
    float* __restrict__ partial) {
  // XCD-partitioned grid (1024 blocks): xcd gets a contiguous 16-row bm strip;
  // consecutive ids share bnr -> concurrent blocks reuse the same B strip in L2.
  int b   = blockIdx.x;
  int xcd = b & 7;
  int idx = b >> 3;               // 0..127
  int bm  = xcd * 16 + (idx & 15);
  int bnr = idx >> 4;             // 0..7

  int tid  = threadIdx.x;
  int lane = tid & 63;
  int wid  = tid >> 6;
  int wr   = wid >> 1;            // 0..1
  int wc   = wid & 1;             // 0..1

  const uchar* Ap = A8 + (size_t)(bm * 8 + wr * 4) * 4096 + (size_t)lane * 32;
  const uchar* Bp = B8 + (size_t)(bnr * 128 + wc * 4) * 4096 + (size_t)lane * 32;

  // persistent A fragments: af[m][kt]
  i32x8 af[4][2];
#pragma unroll
  for (int m = 0; m < 4; ++m)
#pragma unroll
    for (int kt = 0; kt < 2; ++kt)
      af[m][kt] = *reinterpret_cast<const i32x8*>(Ap + m * 4096 + kt * 2048);

  float v[16];
#pragma unroll
  for (int j = 0; j < 16; ++j) v[j] = 0.f;

  const f32x4 zero4 = {0.f, 0.f, 0.f, 0.f};

#define LOADB(dst, t)                                                          \
  {                                                                            \
    _Pragma("unroll") for (int n = 0; n < 4; ++n)                              \
        _Pragma("unroll") for (int kt = 0; kt < 2; ++kt)                       \
            dst[n][kt] = *reinterpret_cast<const i32x8*>(                      \
                Bp + (size_t)(t)*32768 + n * 4096 + kt * 2048);                \
  }

#define COMPUTE(bf)                                                            \
  {                                                                            \
    _Pragma("unroll") for (int m = 0; m < 4; ++m)                              \
        _Pragma("unroll") for (int n = 0; n < 4; ++n) {                        \
      f32x4 acc = __builtin_amdgcn_mfma_scale_f32_16x16x128_f8f6f4(            \
          af[m][0], bf[n][0], zero4, 0, 0, 0, 0x7F7F7F7F, 0, 0x7F7F7F7F);      \
      acc = __builtin_amdgcn_mfma_scale_f32_16x16x128_f8f6f4(                  \
          af[m][1], bf[n][1], acc, 0, 0, 0, 0x7F7F7F7F, 0, 0x7F7F7F7F);        \
      _Pragma("unroll") for (int r = 0; r < 4; ++r)                            \
          v[m * 4 + r] += EXP2(acc[r]);                                        \
    }                                                                          \
  }

  i32x8 bfA[4][2], bfB[4][2];
  LOADB(bfA, 0);
#pragma unroll
  for (int it = 0; it < 8; ++it) {
    LOADB(bfB, 2 * it + 1);        // prefetch odd tile
    COMPUTE(bfA);                  // compute even tile
    if (it < 7) LOADB(bfA, 2 * it + 2);
    COMPUTE(bfB);                  // compute odd tile
  }
#undef LOADB
#undef COMPUTE

  // ---- one butterfly-bisect over the 16 fragment columns (15 shfl) ----
#pragma unroll
  for (int s = 0; s < 4; ++s) {
    const int len = 16 >> s;
    const int bit = (lane >> s) & 1;
#pragma unroll
    for (int t = 0; t < 8; ++t) {
      if (t < (len >> 1)) {
        float a = v[2 * t], b2 = v[2 * t + 1];
        float recv = __shfl_xor(bit ? a : b2, 1 << s);
        v[t] = (bit ? b2 : a) + recv;
      }
    }
  }
  {
    int j     = lane & 15;
    int sub   = lane >> 4;
    int row   = bm * BM + wr * 64 + (j >> 2) * 16 + sub * 4 + (j & 3);
    int chunk = (bnr << 1) | wc;
    partial[(size_t)row * NCHUNK + chunk] = v[0];
  }
}

// ---------------- Kernel C: per-row finish: log(sum) - exact diag ----------
// 4 threads per row read the 16 partial chunks.
__global__ void row_finish(const float* __restrict__ partial,
                           const float* __restrict__ dlog,
                           float* __restrict__ rowloss) {
  int tid = threadIdx.x;
  int row = blockIdx.x * 64 + (tid >> 2);
  int q   = tid & 3;
  float4 p = reinterpret_cast<const float4*>(partial + (size_t)row * NCHUNK)[q];
  float s = p.x + p.y + p.z + p.w;
  s += __shfl_xor(s, 1);
  s += __shfl_xor(s, 2);
  if (q == 0) rowloss[row] = logf(s) - dlog[row];
}

// ---------------- Kernel D: mean over rows -> d_out[0] ----------------
__global__ void final_reduce(const float* __restrict__ rl, float* __restrict__ out) {
  __shared__ float sm[16];
  float s = 0.f;
  for (int i = threadIdx.x; i < BROWS; i += 1024) s += rl[i];
#pragma unroll
  for (int m = 1; m < 64; m <<= 1) s += __shfl_xor(s, m);
  int wid = threadIdx.x >> 6, lane = threadIdx.x & 63;
  if (lane == 0) sm[wid] = s;
  __syncthreads();
  if (wid == 0) {
    float v = (lane < 16) ? sm[lane] : 0.f;
#pragma unroll
    for (int m = 1; m < 16; m <<= 1) v += __shfl_xor(v, m);
    if (lane == 0) out[0] = v / (float)BROWS;
  }
}

extern "C" void kernel_launch(void* const* d_in, const int* in_sizes, int n_in,
                              void* d_out, int out_size, void* d_ws, size_t ws_size,
                              hipStream_t stream) {
  const float* outputs = (const float*)d_in[0];
  const float* targets = (const float*)d_in[1];
  float* out = (float*)d_out;
  char* ws = (char*)d_ws;

  uchar* o8      = (uchar*)ws;                                      // 4 MB (tiled)
  uchar* t8      = (uchar*)(ws + (size_t)4 * 1024 * 1024);          // 4 MB (tiled)
  float* partial = (float*)(ws + (size_t)8 * 1024 * 1024);          // 1 MB
  float* dlog    = (float*)(ws + (size_t)10 * 1024 * 1024);         // 64 KB
  float* rowloss = (float*)(ws + (size_t)10 * 1024 * 1024 + 65536); // 64 KB

  normalize_both<<<BROWS / 4, 256, 0, stream>>>(outputs, targets, o8, t8, dlog);
  gemm_expsum<<<NBM * NBNR, 256, 0, stream>>>(o8, t8, partial);
  row_finish<<<BROWS / 64, 256, 0, stream>>>(partial, dlog, rowloss);
  final_reduce<<<1, 1024, 0, stream>>>(rowloss, out);
}